// Round 13
// baseline (63.097 us; speedup 1.0000x reference)
//
#include <hip/hip_runtime.h>

// Problem: B=8, N=2048, K=32, C=256, COND=512 — ALL FLOAT32 I/O, coords int32.
// Output: f32 [8,2048,256]
// ws footprint deliberately == r11's proven 8552448 bytes (gbp 32K + Wp 128K
// + nnf 8M). r12 grew it by 96KB and post-timing diverged — suspected OOB
// write past ws_size corrupting a neighboring buffer across replays.

typedef unsigned short u16;
typedef unsigned int u32;

typedef __attribute__((ext_vector_type(8))) __bf16 bf16x8;
typedef __attribute__((ext_vector_type(4))) __bf16 bf16x4;
typedef __attribute__((ext_vector_type(4))) float f32x4;
typedef __attribute__((ext_vector_type(2))) float f32x2;
typedef __attribute__((ext_vector_type(4))) u16 u16x4;

__device__ __forceinline__ float b2f(u16 u) {
  union { u32 i; float f; } x; x.i = ((u32)u) << 16; return x.f;
}

// ---------------------------------------------------------------------------
// K0: prep.
//  blocks  0..31 : W_film repack to MFMA-B fragment order (bf16)
//  blocks 32..47 : cond GEMM partials — block (kh,ch) owns the 256k × 64col
//                  tile of Wc, reads it ONCE, computes partials for ALL 8
//                  batches (1 MB total Wc traffic vs 16 MB in the per-batch
//                  layout):
//                  gbp[(kh*8+b)*512 + ch*64+col] =
//                      sum_{kl<256} cond[b][kh*256+kl] * Wc[kh*256+kl][ch*64+col]
// ---------------------------------------------------------------------------
__global__ __launch_bounds__(256) void k_prep(const float* __restrict__ Wf,
                                              u16* __restrict__ Wp,
                                              const float* __restrict__ cond,
                                              const float* __restrict__ Wc,
                                              float* __restrict__ gbp) {
  int blk = blockIdx.x;
  int tid = threadIdx.x;
  if (blk < 32) {
    int i0 = blk * 2048 + tid;
    #pragma unroll
    for (int u = 0; u < 8; ++u) {
      int i = i0 + u * 256;
      int j  = i & 7;
      int l  = (i >> 3) & 63;
      int ks = (i >> 9) & 7;
      int ct = i >> 12;
      int k   = ks * 32 + ((l >> 4) << 3) + j;
      int col = ct * 16 + (l & 15);
      __bf16 b = (__bf16)Wf[k * 256 + col];
      Wp[i] = *(u16*)&b;
    }
  } else {
    int idx = blk - 32;          // 0..15
    int kh = idx >> 3;           // k-half 0..1 (256 k's)
    int ch = idx & 7;            // col-chunk 0..7 (64 cols)

    __shared__ float cf[2048];   // [b][kl]  8 x 256
    __shared__ float red[2048];  // [ks][b*64+col]  4 x 512

    // stage cond[b][kh*256+kl]
    #pragma unroll
    for (int u = 0; u < 8; ++u) {
      int i = u * 256 + tid;
      cf[i] = cond[(i >> 8) * 512 + kh * 256 + (i & 255)];
    }
    __syncthreads();

    int col = tid & 63;
    int ks  = tid >> 6;          // 0..3, each covers 64 k's
    float acc[8] = {0.f,0.f,0.f,0.f,0.f,0.f,0.f,0.f};
    #pragma unroll 4
    for (int t = 0; t < 64; ++t) {
      int kl = ks * 64 + t;
      float wv = Wc[(kh * 256 + kl) * 512 + ch * 64 + col];
      #pragma unroll
      for (int b = 0; b < 8; ++b)
        acc[b] += cf[b * 256 + kl] * wv;
    }
    #pragma unroll
    for (int b = 0; b < 8; ++b)
      red[ks * 512 + b * 64 + col] = acc[b];
    __syncthreads();

    #pragma unroll
    for (int u = 0; u < 2; ++u) {
      int o = u * 256 + tid;     // (b = o>>6, col2 = o&63)
      float s = red[o] + red[512 + o] + red[1024 + o] + red[1536 + o];
      gbp[(kh * 8 + (o >> 6)) * 512 + ch * 64 + (o & 63)] = s;
    }
  }
}

// ---------------------------------------------------------------------------
// K1: nnf = bf16( relu(LN(node_feats @ W_film + b_film) * gamma + beta) )
// (byte-identical to r11 — proven.) 512 blocks × 4 waves, 32 rows/block.
// ---------------------------------------------------------------------------
__global__ __launch_bounds__(256) void k_film(const float* __restrict__ A,
                                              const u16* __restrict__ Wp,
                                              const float* __restrict__ bfm,
                                              const float* __restrict__ gbp,
                                              const float* __restrict__ bcond,
                                              u16* __restrict__ nnf) {
  const int tid = threadIdx.x;
  const int l = tid & 63;
  const int w = tid >> 6;
  const int row0 = blockIdx.x * 32;   // 512 blocks
  const int b = row0 >> 11;

  __shared__ u16 As[32 * 264];
  __shared__ float red[4][2][4][2][4];  // [wave][rb][group][s|q][r]

  #pragma unroll
  for (int u = 0; u < 8; ++u) {
    int f = u * 256 + tid;            // f32x4 index
    int row = f >> 6;
    int col = (f & 63) * 4;
    f32x4 v = *(const f32x4*)(A + (size_t)(row0 + row) * 256 + col);
    bf16x4 pk;
    pk[0] = (__bf16)v.x; pk[1] = (__bf16)v.y;
    pk[2] = (__bf16)v.z; pk[3] = (__bf16)v.w;
    *(bf16x4*)(As + row * 264 + col) = pk;
  }
  __syncthreads();

  f32x4 acc[2][4];
  #pragma unroll
  for (int rb = 0; rb < 2; ++rb)
    #pragma unroll
    for (int c = 0; c < 4; ++c) {
      acc[rb][c].x = 0.f; acc[rb][c].y = 0.f;
      acc[rb][c].z = 0.f; acc[rb][c].w = 0.f;
    }

  const u16* asrc = As + (l & 15) * 264 + ((l >> 4) << 3);
  const u16* wl = Wp + (size_t)l * 8;

  #pragma unroll
  for (int ks = 0; ks < 8; ++ks) {
    bf16x8 af0 = *(const bf16x8*)(asrc + ks * 32);
    bf16x8 af1 = *(const bf16x8*)(asrc + 16 * 264 + ks * 32);
    #pragma unroll
    for (int c = 0; c < 4; ++c) {
      int ct = w * 4 + c;
      bf16x8 bfr = *(const bf16x8*)(wl + ((size_t)(ct * 8 + ks)) * 512);
      acc[0][c] = __builtin_amdgcn_mfma_f32_16x16x32_bf16(af0, bfr, acc[0][c], 0, 0, 0);
      acc[1][c] = __builtin_amdgcn_mfma_f32_16x16x32_bf16(af1, bfr, acc[1][c], 0, 0, 0);
    }
  }

  const int g = l >> 4;
  #pragma unroll
  for (int rb = 0; rb < 2; ++rb) {
    float s[4] = {0.f, 0.f, 0.f, 0.f};
    float q[4] = {0.f, 0.f, 0.f, 0.f};
    #pragma unroll
    for (int c = 0; c < 4; ++c) {
      float bcol = bfm[(w * 4 + c) * 16 + (l & 15)];
      #pragma unroll
      for (int r = 0; r < 4; ++r) {
        float v = acc[rb][c][r] + bcol;
        acc[rb][c][r] = v;
        s[r] += v;
        q[r] += v * v;
      }
    }
    #pragma unroll
    for (int m = 1; m < 16; m <<= 1) {
      #pragma unroll
      for (int r = 0; r < 4; ++r) {
        s[r] += __shfl_xor(s[r], m);
        q[r] += __shfl_xor(q[r], m);
      }
    }
    if ((l & 15) == 0) {
      #pragma unroll
      for (int r = 0; r < 4; ++r) {
        red[w][rb][g][0][r] = s[r];
        red[w][rb][g][1][r] = q[r];
      }
    }
  }
  __syncthreads();

  // hoisted gamma/beta per col: 2 k-partials + bias
  float ga[4], be[4];
  #pragma unroll
  for (int c = 0; c < 4; ++c) {
    int col = (w * 4 + c) * 16 + (l & 15);
    ga[c] = gbp[b * 512 + col] + gbp[(8 + b) * 512 + col] + bcond[col] + 1.0f;
    be[c] = gbp[b * 512 + 256 + col] + gbp[(8 + b) * 512 + 256 + col] + bcond[256 + col];
  }

  #pragma unroll
  for (int rb = 0; rb < 2; ++rb) {
    float mu[4], rs[4];
    #pragma unroll
    for (int r = 0; r < 4; ++r) {
      float ss = red[0][rb][g][0][r] + red[1][rb][g][0][r] +
                 red[2][rb][g][0][r] + red[3][rb][g][0][r];
      float qq = red[0][rb][g][1][r] + red[1][rb][g][1][r] +
                 red[2][rb][g][1][r] + red[3][rb][g][1][r];
      mu[r] = ss * (1.0f / 256.0f);
      float var = qq * (1.0f / 256.0f) - mu[r] * mu[r];
      rs[r] = rsqrtf(var + 1e-5f);
    }
    const int rowb = row0 + rb * 16 + (g << 2);
    #pragma unroll
    for (int c = 0; c < 4; ++c) {
      int col = (w * 4 + c) * 16 + (l & 15);
      #pragma unroll
      for (int r = 0; r < 4; ++r) {
        float h = (acc[rb][c][r] - mu[r]) * rs[r];
        float o = fmaxf(h * ga[c] + be[c], 0.f);
        ((__bf16*)nnf)[(size_t)(rowb + r) * 256 + col] = (__bf16)o;
      }
    }
  }
}

// ---------------------------------------------------------------------------
// K2: out = relu(nnf + sum_k ew[k]*nnf[coords[k]])  — column-quarter sliced,
// QUAD-ROW waves + LDS idx/ew broadcast (r9 structure — frozen, proven).
// ---------------------------------------------------------------------------
__global__ __launch_bounds__(256) void k_gather(const u16* __restrict__ nnf,
                                                const float* __restrict__ wts,
                                                const float* __restrict__ prm,
                                                const int* __restrict__ coords,
                                                float* __restrict__ out) {
  const int q  = blockIdx.x >> 10;    // 0..3
  const int rg = blockIdx.x & 1023;   // 16-row group
  const int tid = threadIdx.x;

  __shared__ int   s_idx[512];        // [16 rows][32 k]
  __shared__ float s_ew[512];

  {
    int base = rg * 512 + tid * 2;
    int2  c2 = *(const int2*)(coords + base);
    f32x2 w2 = __builtin_nontemporal_load((const f32x2*)(wts + base));
    f32x2 p2 = __builtin_nontemporal_load((const f32x2*)(prm + base));
    s_idx[tid * 2]     = c2.x;
    s_idx[tid * 2 + 1] = c2.y;
    s_ew[tid * 2]      = w2.x * p2.x;
    s_ew[tid * 2 + 1]  = w2.y * p2.y;
  }
  __syncthreads();

  const int w = tid >> 6;
  const int l = tid & 63;
  const int g = l >> 4;
  const int m = l & 15;
  const int rl = w * 4 + g;           // row-local 0..15
  const int row = rg * 16 + rl;       // 0..16383
  const int kbase = rl * 32;
  const u16* colp = nnf + q * 64 + m * 4;

  u16x4 v[32];
  #pragma unroll
  for (int k = 0; k < 32; ++k) {
    int idx = s_idx[kbase + k];       // uniform per 16-lane group
    v[k] = *(const u16x4*)(colp + ((size_t)idx << 8));
  }

  float acc[4] = {0.f, 0.f, 0.f, 0.f};
  #pragma unroll
  for (int k = 0; k < 32; ++k) {
    float wgt = s_ew[kbase + k];
    #pragma unroll
    for (int j = 0; j < 4; ++j)
      acc[j] += wgt * b2f(v[k][j]);
  }

  u16x4 sv = *(const u16x4*)(colp + ((size_t)row << 8));
  f32x4 o;
  o.x = fmaxf(b2f(sv.x) + acc[0], 0.f);
  o.y = fmaxf(b2f(sv.y) + acc[1], 0.f);
  o.z = fmaxf(b2f(sv.z) + acc[2], 0.f);
  o.w = fmaxf(b2f(sv.w) + acc[3], 0.f);
  __builtin_nontemporal_store(o, (f32x4*)(out + (size_t)row * 256 + q * 64 + m * 4));
}

// ---------------------------------------------------------------------------
extern "C" void kernel_launch(void* const* d_in, const int* in_sizes, int n_in,
                              void* d_out, int out_size, void* d_ws, size_t ws_size,
                              hipStream_t stream) {
  const float* node = (const float*)d_in[0];
  const float* cond = (const float*)d_in[1];
  const float* Wc   = (const float*)d_in[2];
  const float* bc   = (const float*)d_in[3];
  const float* Wf   = (const float*)d_in[4];
  const float* bf   = (const float*)d_in[5];
  const float* wts  = (const float*)d_in[6];
  const float* prm  = (const float*)d_in[7];
  const int* coords = (const int*)d_in[8];
  float* out = (float*)d_out;

  char* ws = (char*)d_ws;
  float* gbp = (float*)ws;                        // 2*8*512 f32 = 32 KB
  u16* Wp    = (u16*)(ws + 32768);                // 128 KB
  u16* nnf   = (u16*)(ws + 32768 + 131072);       // 8 MB  (total 8552448 B)

  k_prep<<<dim3(48), dim3(256), 0, stream>>>(Wf, Wp, cond, Wc, gbp);
  k_film<<<dim3(512), dim3(256), 0, stream>>>(node, Wp, bf, gbp, bc, nnf);
  k_gather<<<dim3(4096), dim3(256), 0, stream>>>(nnf, wts, prm, coords, out);
}

// Round 14
// 47.935 us; speedup vs baseline: 1.3163x; 1.3163x over previous
//
#include <hip/hip_runtime.h>

// Problem: B=8, N=2048, K=32, C=256, COND=512 — ALL FLOAT32 I/O, coords int32.
// Output: f32 [8,2048,256]
// ws footprint == r11/r13-proven 8552448 bytes (gbp 32K + Wp 128K + nnf 8M).

typedef unsigned short u16;
typedef unsigned int u32;

typedef __attribute__((ext_vector_type(8))) __bf16 bf16x8;
typedef __attribute__((ext_vector_type(4))) __bf16 bf16x4;
typedef __attribute__((ext_vector_type(4))) float f32x4;
typedef __attribute__((ext_vector_type(2))) float f32x2;
typedef __attribute__((ext_vector_type(4))) u16 u16x4;

__device__ __forceinline__ float b2f(u16 u) {
  union { u32 i; float f; } x; x.i = ((u32)u) << 16; return x.f;
}

// ---------------------------------------------------------------------------
// K0: prep.
//  blocks  0..31 : W_film repack to MFMA-B fragment order (bf16)
//  blocks 32..95 : cond GEMM partials — block (kh∈{0,1}, ch∈{0..31}) owns a
//                  256k × 16col tile of Wc. 16 k-groups (ks=tid>>4) → the
//                  t-loop is 16 INDEPENDENT loads (fully unrolled, all in
//                  flight) instead of r13's 64-step serial chain at 16 blocks.
//                  gbp[(kh*8+b)*512 + ch*16+col] =
//                    sum_{kl<256} cond[b][kh*256+kl] * Wc[kh*256+kl][ch*16+col]
// ---------------------------------------------------------------------------
__global__ __launch_bounds__(256) void k_prep(const float* __restrict__ Wf,
                                              u16* __restrict__ Wp,
                                              const float* __restrict__ cond,
                                              const float* __restrict__ Wc,
                                              float* __restrict__ gbp) {
  int blk = blockIdx.x;
  int tid = threadIdx.x;
  if (blk < 32) {
    int i0 = blk * 2048 + tid;
    #pragma unroll
    for (int u = 0; u < 8; ++u) {
      int i = i0 + u * 256;
      int j  = i & 7;
      int l  = (i >> 3) & 63;
      int ks = (i >> 9) & 7;
      int ct = i >> 12;
      int k   = ks * 32 + ((l >> 4) << 3) + j;
      int col = ct * 16 + (l & 15);
      __bf16 b = (__bf16)Wf[k * 256 + col];
      Wp[i] = *(u16*)&b;
    }
  } else {
    int idx = blk - 32;          // 0..63
    int kh = idx >> 5;           // k-half 0..1 (256 k's)
    int ch = idx & 31;           // col-chunk 0..31 (16 cols)

    __shared__ float cf[2048];   // [b][kl]  8 x 256
    __shared__ float red[2048];  // [ks][b*16+col]  16 x 128

    // stage cond[b][kh*256+kl] (coalesced: 256 consecutive per u)
    #pragma unroll
    for (int u = 0; u < 8; ++u) {
      int i = u * 256 + tid;
      cf[i] = cond[(i >> 8) * 512 + kh * 256 + (i & 255)];
    }
    __syncthreads();

    int col = tid & 15;
    int ks  = tid >> 4;          // 0..15, each covers 16 k's
    float acc[8] = {0.f,0.f,0.f,0.f,0.f,0.f,0.f,0.f};
    #pragma unroll
    for (int t = 0; t < 16; ++t) {
      int kl = ks * 16 + t;
      float wv = Wc[(kh * 256 + kl) * 512 + ch * 16 + col];
      #pragma unroll
      for (int b = 0; b < 8; ++b)
        acc[b] += cf[b * 256 + kl] * wv;
    }
    #pragma unroll
    for (int b = 0; b < 8; ++b)
      red[ks * 128 + b * 16 + col] = acc[b];
    __syncthreads();

    if (tid < 128) {             // b = tid>>4, col2 = tid&15
      float s = 0.f;
      #pragma unroll
      for (int p = 0; p < 16; ++p)
        s += red[p * 128 + tid];
      gbp[(kh * 8 + (tid >> 4)) * 512 + ch * 16 + (tid & 15)] = s;
    }
  }
}

// ---------------------------------------------------------------------------
// K1: nnf = bf16( relu(LN(node_feats @ W_film + b_film) * gamma + beta) )
// (byte-identical to r11/r13 — proven.) 512 blocks × 4 waves, 32 rows/block.
// ---------------------------------------------------------------------------
__global__ __launch_bounds__(256) void k_film(const float* __restrict__ A,
                                              const u16* __restrict__ Wp,
                                              const float* __restrict__ bfm,
                                              const float* __restrict__ gbp,
                                              const float* __restrict__ bcond,
                                              u16* __restrict__ nnf) {
  const int tid = threadIdx.x;
  const int l = tid & 63;
  const int w = tid >> 6;
  const int row0 = blockIdx.x * 32;   // 512 blocks
  const int b = row0 >> 11;

  __shared__ u16 As[32 * 264];
  __shared__ float red[4][2][4][2][4];  // [wave][rb][group][s|q][r]

  #pragma unroll
  for (int u = 0; u < 8; ++u) {
    int f = u * 256 + tid;            // f32x4 index
    int row = f >> 6;
    int col = (f & 63) * 4;
    f32x4 v = *(const f32x4*)(A + (size_t)(row0 + row) * 256 + col);
    bf16x4 pk;
    pk[0] = (__bf16)v.x; pk[1] = (__bf16)v.y;
    pk[2] = (__bf16)v.z; pk[3] = (__bf16)v.w;
    *(bf16x4*)(As + row * 264 + col) = pk;
  }
  __syncthreads();

  f32x4 acc[2][4];
  #pragma unroll
  for (int rb = 0; rb < 2; ++rb)
    #pragma unroll
    for (int c = 0; c < 4; ++c) {
      acc[rb][c].x = 0.f; acc[rb][c].y = 0.f;
      acc[rb][c].z = 0.f; acc[rb][c].w = 0.f;
    }

  const u16* asrc = As + (l & 15) * 264 + ((l >> 4) << 3);
  const u16* wl = Wp + (size_t)l * 8;

  #pragma unroll
  for (int ks = 0; ks < 8; ++ks) {
    bf16x8 af0 = *(const bf16x8*)(asrc + ks * 32);
    bf16x8 af1 = *(const bf16x8*)(asrc + 16 * 264 + ks * 32);
    #pragma unroll
    for (int c = 0; c < 4; ++c) {
      int ct = w * 4 + c;
      bf16x8 bfr = *(const bf16x8*)(wl + ((size_t)(ct * 8 + ks)) * 512);
      acc[0][c] = __builtin_amdgcn_mfma_f32_16x16x32_bf16(af0, bfr, acc[0][c], 0, 0, 0);
      acc[1][c] = __builtin_amdgcn_mfma_f32_16x16x32_bf16(af1, bfr, acc[1][c], 0, 0, 0);
    }
  }

  const int g = l >> 4;
  #pragma unroll
  for (int rb = 0; rb < 2; ++rb) {
    float s[4] = {0.f, 0.f, 0.f, 0.f};
    float q[4] = {0.f, 0.f, 0.f, 0.f};
    #pragma unroll
    for (int c = 0; c < 4; ++c) {
      float bcol = bfm[(w * 4 + c) * 16 + (l & 15)];
      #pragma unroll
      for (int r = 0; r < 4; ++r) {
        float v = acc[rb][c][r] + bcol;
        acc[rb][c][r] = v;
        s[r] += v;
        q[r] += v * v;
      }
    }
    #pragma unroll
    for (int m = 1; m < 16; m <<= 1) {
      #pragma unroll
      for (int r = 0; r < 4; ++r) {
        s[r] += __shfl_xor(s[r], m);
        q[r] += __shfl_xor(q[r], m);
      }
    }
    if ((l & 15) == 0) {
      #pragma unroll
      for (int r = 0; r < 4; ++r) {
        red[w][rb][g][0][r] = s[r];
        red[w][rb][g][1][r] = q[r];
      }
    }
  }
  __syncthreads();

  // hoisted gamma/beta per col: 2 k-partials + bias
  float ga[4], be[4];
  #pragma unroll
  for (int c = 0; c < 4; ++c) {
    int col = (w * 4 + c) * 16 + (l & 15);
    ga[c] = gbp[b * 512 + col] + gbp[(8 + b) * 512 + col] + bcond[col] + 1.0f;
    be[c] = gbp[b * 512 + 256 + col] + gbp[(8 + b) * 512 + 256 + col] + bcond[256 + col];
  }

  #pragma unroll
  for (int rb = 0; rb < 2; ++rb) {
    float mu[4], rs[4];
    #pragma unroll
    for (int r = 0; r < 4; ++r) {
      float ss = red[0][rb][g][0][r] + red[1][rb][g][0][r] +
                 red[2][rb][g][0][r] + red[3][rb][g][0][r];
      float qq = red[0][rb][g][1][r] + red[1][rb][g][1][r] +
                 red[2][rb][g][1][r] + red[3][rb][g][1][r];
      mu[r] = ss * (1.0f / 256.0f);
      float var = qq * (1.0f / 256.0f) - mu[r] * mu[r];
      rs[r] = rsqrtf(var + 1e-5f);
    }
    const int rowb = row0 + rb * 16 + (g << 2);
    #pragma unroll
    for (int c = 0; c < 4; ++c) {
      int col = (w * 4 + c) * 16 + (l & 15);
      #pragma unroll
      for (int r = 0; r < 4; ++r) {
        float h = (acc[rb][c][r] - mu[r]) * rs[r];
        float o = fmaxf(h * ga[c] + be[c], 0.f);
        ((__bf16*)nnf)[(size_t)(rowb + r) * 256 + col] = (__bf16)o;
      }
    }
  }
}

// ---------------------------------------------------------------------------
// K2: out = relu(nnf + sum_k ew[k]*nnf[coords[k]])  — column-quarter sliced,
// QUAD-ROW waves + LDS idx/ew broadcast (r9 structure — frozen, proven).
// ---------------------------------------------------------------------------
__global__ __launch_bounds__(256) void k_gather(const u16* __restrict__ nnf,
                                                const float* __restrict__ wts,
                                                const float* __restrict__ prm,
                                                const int* __restrict__ coords,
                                                float* __restrict__ out) {
  const int q  = blockIdx.x >> 10;    // 0..3
  const int rg = blockIdx.x & 1023;   // 16-row group
  const int tid = threadIdx.x;

  __shared__ int   s_idx[512];        // [16 rows][32 k]
  __shared__ float s_ew[512];

  {
    int base = rg * 512 + tid * 2;
    int2  c2 = *(const int2*)(coords + base);
    f32x2 w2 = __builtin_nontemporal_load((const f32x2*)(wts + base));
    f32x2 p2 = __builtin_nontemporal_load((const f32x2*)(prm + base));
    s_idx[tid * 2]     = c2.x;
    s_idx[tid * 2 + 1] = c2.y;
    s_ew[tid * 2]      = w2.x * p2.x;
    s_ew[tid * 2 + 1]  = w2.y * p2.y;
  }
  __syncthreads();

  const int w = tid >> 6;
  const int l = tid & 63;
  const int g = l >> 4;
  const int m = l & 15;
  const int rl = w * 4 + g;           // row-local 0..15
  const int row = rg * 16 + rl;       // 0..16383
  const int kbase = rl * 32;
  const u16* colp = nnf + q * 64 + m * 4;

  u16x4 v[32];
  #pragma unroll
  for (int k = 0; k < 32; ++k) {
    int idx = s_idx[kbase + k];       // uniform per 16-lane group
    v[k] = *(const u16x4*)(colp + ((size_t)idx << 8));
  }

  float acc[4] = {0.f, 0.f, 0.f, 0.f};
  #pragma unroll
  for (int k = 0; k < 32; ++k) {
    float wgt = s_ew[kbase + k];
    #pragma unroll
    for (int j = 0; j < 4; ++j)
      acc[j] += wgt * b2f(v[k][j]);
  }

  u16x4 sv = *(const u16x4*)(colp + ((size_t)row << 8));
  f32x4 o;
  o.x = fmaxf(b2f(sv.x) + acc[0], 0.f);
  o.y = fmaxf(b2f(sv.y) + acc[1], 0.f);
  o.z = fmaxf(b2f(sv.z) + acc[2], 0.f);
  o.w = fmaxf(b2f(sv.w) + acc[3], 0.f);
  __builtin_nontemporal_store(o, (f32x4*)(out + (size_t)row * 256 + q * 64 + m * 4));
}

// ---------------------------------------------------------------------------
extern "C" void kernel_launch(void* const* d_in, const int* in_sizes, int n_in,
                              void* d_out, int out_size, void* d_ws, size_t ws_size,
                              hipStream_t stream) {
  const float* node = (const float*)d_in[0];
  const float* cond = (const float*)d_in[1];
  const float* Wc   = (const float*)d_in[2];
  const float* bc   = (const float*)d_in[3];
  const float* Wf   = (const float*)d_in[4];
  const float* bf   = (const float*)d_in[5];
  const float* wts  = (const float*)d_in[6];
  const float* prm  = (const float*)d_in[7];
  const int* coords = (const int*)d_in[8];
  float* out = (float*)d_out;

  char* ws = (char*)d_ws;
  float* gbp = (float*)ws;                        // 2*8*512 f32 = 32 KB
  u16* Wp    = (u16*)(ws + 32768);                // 128 KB
  u16* nnf   = (u16*)(ws + 32768 + 131072);       // 8 MB  (total 8552448 B)

  k_prep<<<dim3(96), dim3(256), 0, stream>>>(Wf, Wp, cond, Wc, gbp);
  k_film<<<dim3(512), dim3(256), 0, stream>>>(node, Wp, bf, gbp, bc, nnf);
  k_gather<<<dim3(4096), dim3(256), 0, stream>>>(nnf, wts, prm, coords, out);
}

// Round 15
// 45.953 us; speedup vs baseline: 1.3731x; 1.0431x over previous
//
#include <hip/hip_runtime.h>

// Problem: B=8, N=2048, K=32, C=256, COND=512 — ALL FLOAT32 I/O, coords int32.
// Output: f32 [8,2048,256]
// ws footprint == proven 8552448 bytes (gbp 32K + Wp 128K + nnf 8M).

typedef unsigned short u16;
typedef unsigned int u32;

typedef __attribute__((ext_vector_type(8))) __bf16 bf16x8;
typedef __attribute__((ext_vector_type(4))) __bf16 bf16x4;
typedef __attribute__((ext_vector_type(4))) float f32x4;
typedef __attribute__((ext_vector_type(2))) float f32x2;
typedef __attribute__((ext_vector_type(4))) u16 u16x4;

__device__ __forceinline__ float b2f(u16 u) {
  union { u32 i; float f; } x; x.i = ((u32)u) << 16; return x.f;
}

// ---------------------------------------------------------------------------
// K0: prep (byte-identical to r14 — proven 48 µs config).
//  blocks  0..31 : W_film repack to MFMA-B fragment order (bf16)
//  blocks 32..95 : cond GEMM partials — block (kh,ch) owns 256k × 16col of Wc,
//                  16 independent loads in flight per thread.
// ---------------------------------------------------------------------------
__global__ __launch_bounds__(256) void k_prep(const float* __restrict__ Wf,
                                              u16* __restrict__ Wp,
                                              const float* __restrict__ cond,
                                              const float* __restrict__ Wc,
                                              float* __restrict__ gbp) {
  int blk = blockIdx.x;
  int tid = threadIdx.x;
  if (blk < 32) {
    int i0 = blk * 2048 + tid;
    #pragma unroll
    for (int u = 0; u < 8; ++u) {
      int i = i0 + u * 256;
      int j  = i & 7;
      int l  = (i >> 3) & 63;
      int ks = (i >> 9) & 7;
      int ct = i >> 12;
      int k   = ks * 32 + ((l >> 4) << 3) + j;
      int col = ct * 16 + (l & 15);
      __bf16 b = (__bf16)Wf[k * 256 + col];
      Wp[i] = *(u16*)&b;
    }
  } else {
    int idx = blk - 32;          // 0..63
    int kh = idx >> 5;           // k-half 0..1 (256 k's)
    int ch = idx & 31;           // col-chunk 0..31 (16 cols)

    __shared__ float cf[2048];   // [b][kl]  8 x 256
    __shared__ float red[2048];  // [ks][b*16+col]  16 x 128

    #pragma unroll
    for (int u = 0; u < 8; ++u) {
      int i = u * 256 + tid;
      cf[i] = cond[(i >> 8) * 512 + kh * 256 + (i & 255)];
    }
    __syncthreads();

    int col = tid & 15;
    int ks  = tid >> 4;          // 0..15, each covers 16 k's
    float acc[8] = {0.f,0.f,0.f,0.f,0.f,0.f,0.f,0.f};
    #pragma unroll
    for (int t = 0; t < 16; ++t) {
      int kl = ks * 16 + t;
      float wv = Wc[(kh * 256 + kl) * 512 + ch * 16 + col];
      #pragma unroll
      for (int b = 0; b < 8; ++b)
        acc[b] += cf[b * 256 + kl] * wv;
    }
    #pragma unroll
    for (int b = 0; b < 8; ++b)
      red[ks * 128 + b * 16 + col] = acc[b];
    __syncthreads();

    if (tid < 128) {             // b = tid>>4, col2 = tid&15
      float s = 0.f;
      #pragma unroll
      for (int p = 0; p < 16; ++p)
        s += red[p * 128 + tid];
      gbp[(kh * 8 + (tid >> 4)) * 512 + ch * 16 + (tid & 15)] = s;
    }
  }
}

// ---------------------------------------------------------------------------
// K1: nnf = bf16( relu(LN(node_feats @ W_film + b_film) * gamma + beta) )
// TLP 2×: 1024 blocks × 256 thr (4 waves), 16 rows/block (was 512×32).
// 4 blocks/CU, 16 waves/CU — stage/MFMA/epilogue phases overlap across
// blocks. A staged to LDS bf16 [16][264] via native-cast cvt_pk. Wave w owns
// col-tiles ct=w*4..w*4+3 (reads only its 32 KB Wp slice).
// D frag: col = ct*16+(l&15), row = row0 + (l>>4)*4 + r
// ---------------------------------------------------------------------------
__global__ __launch_bounds__(256) void k_film(const float* __restrict__ A,
                                              const u16* __restrict__ Wp,
                                              const float* __restrict__ bfm,
                                              const float* __restrict__ gbp,
                                              const float* __restrict__ bcond,
                                              u16* __restrict__ nnf) {
  const int tid = threadIdx.x;
  const int l = tid & 63;
  const int w = tid >> 6;
  const int row0 = blockIdx.x * 16;   // 1024 blocks
  const int b = row0 >> 11;

  __shared__ u16 As[16 * 264];
  __shared__ float red[4][4][2][4];   // [wave][group][s|q][r]

  // Stage: flat coalesced, f32 -> bf16 (cvt_pk), one 8B store per iter
  #pragma unroll
  for (int u = 0; u < 4; ++u) {
    int f = u * 256 + tid;            // f32x4 index
    int row = f >> 6;
    int col = (f & 63) * 4;
    f32x4 v = *(const f32x4*)(A + (size_t)(row0 + row) * 256 + col);
    bf16x4 pk;
    pk[0] = (__bf16)v.x; pk[1] = (__bf16)v.y;
    pk[2] = (__bf16)v.z; pk[3] = (__bf16)v.w;
    *(bf16x4*)(As + row * 264 + col) = pk;
  }
  __syncthreads();

  f32x4 acc[4];
  #pragma unroll
  for (int c = 0; c < 4; ++c) {
    acc[c].x = 0.f; acc[c].y = 0.f; acc[c].z = 0.f; acc[c].w = 0.f;
  }

  const u16* asrc = As + (l & 15) * 264 + ((l >> 4) << 3);
  const u16* wl = Wp + (size_t)l * 8;

  #pragma unroll
  for (int ks = 0; ks < 8; ++ks) {
    bf16x8 af = *(const bf16x8*)(asrc + ks * 32);
    #pragma unroll
    for (int c = 0; c < 4; ++c) {
      int ct = w * 4 + c;
      bf16x8 bfr = *(const bf16x8*)(wl + ((size_t)(ct * 8 + ks)) * 512);
      acc[c] = __builtin_amdgcn_mfma_f32_16x16x32_bf16(af, bfr, acc[c], 0, 0, 0);
    }
  }

  const int g = l >> 4;
  float s[4] = {0.f, 0.f, 0.f, 0.f};
  float q[4] = {0.f, 0.f, 0.f, 0.f};
  #pragma unroll
  for (int c = 0; c < 4; ++c) {
    float bcol = bfm[(w * 4 + c) * 16 + (l & 15)];
    #pragma unroll
    for (int r = 0; r < 4; ++r) {
      float v = acc[c][r] + bcol;
      acc[c][r] = v;
      s[r] += v;
      q[r] += v * v;
    }
  }
  #pragma unroll
  for (int m = 1; m < 16; m <<= 1) {
    #pragma unroll
    for (int r = 0; r < 4; ++r) {
      s[r] += __shfl_xor(s[r], m);
      q[r] += __shfl_xor(q[r], m);
    }
  }
  if ((l & 15) == 0) {
    #pragma unroll
    for (int r = 0; r < 4; ++r) {
      red[w][g][0][r] = s[r];
      red[w][g][1][r] = q[r];
    }
  }
  __syncthreads();

  // hoisted gamma/beta per col: 2 k-partials + bias
  float ga[4], be[4];
  #pragma unroll
  for (int c = 0; c < 4; ++c) {
    int col = (w * 4 + c) * 16 + (l & 15);
    ga[c] = gbp[b * 512 + col] + gbp[(8 + b) * 512 + col] + bcond[col] + 1.0f;
    be[c] = gbp[b * 512 + 256 + col] + gbp[(8 + b) * 512 + 256 + col] + bcond[256 + col];
  }

  float mu[4], rs[4];
  #pragma unroll
  for (int r = 0; r < 4; ++r) {
    float ss = red[0][g][0][r] + red[1][g][0][r] + red[2][g][0][r] + red[3][g][0][r];
    float qq = red[0][g][1][r] + red[1][g][1][r] + red[2][g][1][r] + red[3][g][1][r];
    mu[r] = ss * (1.0f / 256.0f);
    float var = qq * (1.0f / 256.0f) - mu[r] * mu[r];
    rs[r] = rsqrtf(var + 1e-5f);
  }

  const int rowb = row0 + (g << 2);
  #pragma unroll
  for (int c = 0; c < 4; ++c) {
    int col = (w * 4 + c) * 16 + (l & 15);
    #pragma unroll
    for (int r = 0; r < 4; ++r) {
      float h = (acc[c][r] - mu[r]) * rs[r];
      float o = fmaxf(h * ga[c] + be[c], 0.f);
      ((__bf16*)nnf)[(size_t)(rowb + r) * 256 + col] = (__bf16)o;
    }
  }
}

// ---------------------------------------------------------------------------
// K2: out = relu(nnf + sum_k ew[k]*nnf[coords[k]])  — column-quarter sliced,
// QUAD-ROW waves + LDS idx/ew broadcast (r9 structure — frozen, proven).
// ---------------------------------------------------------------------------
__global__ __launch_bounds__(256) void k_gather(const u16* __restrict__ nnf,
                                                const float* __restrict__ wts,
                                                const float* __restrict__ prm,
                                                const int* __restrict__ coords,
                                                float* __restrict__ out) {
  const int q  = blockIdx.x >> 10;    // 0..3
  const int rg = blockIdx.x & 1023;   // 16-row group
  const int tid = threadIdx.x;

  __shared__ int   s_idx[512];        // [16 rows][32 k]
  __shared__ float s_ew[512];

  {
    int base = rg * 512 + tid * 2;
    int2  c2 = *(const int2*)(coords + base);
    f32x2 w2 = __builtin_nontemporal_load((const f32x2*)(wts + base));
    f32x2 p2 = __builtin_nontemporal_load((const f32x2*)(prm + base));
    s_idx[tid * 2]     = c2.x;
    s_idx[tid * 2 + 1] = c2.y;
    s_ew[tid * 2]      = w2.x * p2.x;
    s_ew[tid * 2 + 1]  = w2.y * p2.y;
  }
  __syncthreads();

  const int w = tid >> 6;
  const int l = tid & 63;
  const int g = l >> 4;
  const int m = l & 15;
  const int rl = w * 4 + g;           // row-local 0..15
  const int row = rg * 16 + rl;       // 0..16383
  const int kbase = rl * 32;
  const u16* colp = nnf + q * 64 + m * 4;

  u16x4 v[32];
  #pragma unroll
  for (int k = 0; k < 32; ++k) {
    int idx = s_idx[kbase + k];       // uniform per 16-lane group
    v[k] = *(const u16x4*)(colp + ((size_t)idx << 8));
  }

  float acc[4] = {0.f, 0.f, 0.f, 0.f};
  #pragma unroll
  for (int k = 0; k < 32; ++k) {
    float wgt = s_ew[kbase + k];
    #pragma unroll
    for (int j = 0; j < 4; ++j)
      acc[j] += wgt * b2f(v[k][j]);
  }

  u16x4 sv = *(const u16x4*)(colp + ((size_t)row << 8));
  f32x4 o;
  o.x = fmaxf(b2f(sv.x) + acc[0], 0.f);
  o.y = fmaxf(b2f(sv.y) + acc[1], 0.f);
  o.z = fmaxf(b2f(sv.z) + acc[2], 0.f);
  o.w = fmaxf(b2f(sv.w) + acc[3], 0.f);
  __builtin_nontemporal_store(o, (f32x4*)(out + (size_t)row * 256 + q * 64 + m * 4));
}

// ---------------------------------------------------------------------------
extern "C" void kernel_launch(void* const* d_in, const int* in_sizes, int n_in,
                              void* d_out, int out_size, void* d_ws, size_t ws_size,
                              hipStream_t stream) {
  const float* node = (const float*)d_in[0];
  const float* cond = (const float*)d_in[1];
  const float* Wc   = (const float*)d_in[2];
  const float* bc   = (const float*)d_in[3];
  const float* Wf   = (const float*)d_in[4];
  const float* bf   = (const float*)d_in[5];
  const float* wts  = (const float*)d_in[6];
  const float* prm  = (const float*)d_in[7];
  const int* coords = (const int*)d_in[8];
  float* out = (float*)d_out;

  char* ws = (char*)d_ws;
  float* gbp = (float*)ws;                        // 2*8*512 f32 = 32 KB
  u16* Wp    = (u16*)(ws + 32768);                // 128 KB
  u16* nnf   = (u16*)(ws + 32768 + 131072);       // 8 MB  (total 8552448 B)

  k_prep<<<dim3(96), dim3(256), 0, stream>>>(Wf, Wp, cond, Wc, gbp);
  k_film<<<dim3(1024), dim3(256), 0, stream>>>(node, Wp, bf, gbp, bc, nnf);
  k_gather<<<dim3(4096), dim3(256), 0, stream>>>(nnf, wts, prm, coords, out);
}